// Round 3
// baseline (87357.465 us; speedup 1.0000x reference)
//
#include <hip/hip_runtime.h>

// Problem constants
#define HH 512
#define BB 128
#define TT 512
#define LL 4
#define JJ 2
#define NBLK 256

typedef _Float16 f16;
typedef __attribute__((ext_vector_type(8))) _Float16 f16x8;
typedef __attribute__((ext_vector_type(4))) float f32x4;

struct KP {
    const float* H0in;
    const float *lin_b, *g0_b, *g1_b;
    const f16 *linT, *g0T, *g1T;
    float *H0out, *H1st; f16 *H1st_h;
    f16 *A0b, *A1b; float *z0b, *z1b;
    float *h0m, *h1m; f16 *h0m_h, *h1m_h;
    float *pipe; f16 *pipe_h;
    unsigned* bars;   // 5 domains x 16 uints: [count, gen, pad...] 64B apart
};

// ---------------------------------------------------------------------------
// Weight convert + transpose: src fp32 [mat][K][N] -> dst fp16 [mat][N][K]
// ---------------------------------------------------------------------------
__global__ __launch_bounds__(256) void wt_transpose_cvt(
    const float* __restrict__ src, f16* __restrict__ dst, int K, int N)
{
    __shared__ f16 tile[32][33];
    const size_t mat = blockIdx.z;
    const float* s = src + mat * (size_t)K * N;
    f16* d = dst + mat * (size_t)K * N;
    const int k0 = blockIdx.x * 32, n0 = blockIdx.y * 32;
    const int tx = threadIdx.x & 31, ty = threadIdx.x >> 5; // 32 x 8
#pragma unroll
    for (int i = 0; i < 4; i++) {
        int k = k0 + ty + 8 * i;
        tile[ty + 8 * i][tx] = (f16)s[(size_t)k * N + n0 + tx];
    }
    __syncthreads();
#pragma unroll
    for (int i = 0; i < 4; i++) {
        int n = n0 + ty + 8 * i;
        d[(size_t)n * K + k0 + tx] = tile[tx][ty + 8 * i];
    }
}

__device__ __forceinline__ f16x8 cvt8(const float* p) {
    const float4 v0 = *(const float4*)p;
    const float4 v1 = *(const float4*)(p + 4);
    f16x8 h;
    h[0] = (f16)v0.x; h[1] = (f16)v0.y; h[2] = (f16)v0.z; h[3] = (f16)v0.w;
    h[4] = (f16)v1.x; h[5] = (f16)v1.y; h[6] = (f16)v1.z; h[7] = (f16)v1.w;
    return h;
}

// ---------------------------------------------------------------------------
// Device-scope sense-reversing barrier. base[0]=count, base[1]=generation.
// Agent-scope atomics + __threadfence() give cross-XCD L2 wb/inv.
// ---------------------------------------------------------------------------
__device__ __forceinline__ void gbar(unsigned* base, unsigned n)
{
    __syncthreads();
    if (threadIdx.x == 0) {
        __threadfence();   // release: drain + make prior writes agent-visible
        unsigned* cnt = base;
        unsigned* gen = base + 1;
        unsigned g = __hip_atomic_load(gen, __ATOMIC_RELAXED, __HIP_MEMORY_SCOPE_AGENT);
        unsigned a = __hip_atomic_fetch_add(cnt, 1u, __ATOMIC_ACQ_REL, __HIP_MEMORY_SCOPE_AGENT);
        if (a == n - 1u) {
            __hip_atomic_store(cnt, 0u, __ATOMIC_RELAXED, __HIP_MEMORY_SCOPE_AGENT);
            __hip_atomic_fetch_add(gen, 1u, __ATOMIC_RELEASE, __HIP_MEMORY_SCOPE_AGENT);
        } else {
            while (__hip_atomic_load(gen, __ATOMIC_RELAXED, __HIP_MEMORY_SCOPE_AGENT) == g)
                __builtin_amdgcn_s_sleep(2);
        }
        __threadfence();   // acquire: invalidate so we see others' writes
    }
    __syncthreads();
}

// ---------------------------------------------------------------------------
// Stage 1 (per unit = 64x64 tile of one cell's lin-GEMM):
// g = sigmoid([h0|h1] @ lin_w + lin_b), M=128(->64), K=1024, N=2048
// unit u: ci=u>>6, mh=(u>>5)&1, nt=u&31
// ---------------------------------------------------------------------------
__device__ void stage1(const KP& P, int d, int j, int lmin,
                       f16 (*Al)[72], f16 (*Bl)[72])
{
    const int tid = threadIdx.x;
    const int u = blockIdx.x;
    const int ci = u >> 6, rem = u & 63, mh = rem >> 5, nt = rem & 31;
    const int l = lmin + ci, t = d - l, w = l * JJ + j;
    const int n0 = nt * 64;

    const f16* h0_16 = nullptr; const float* h0_32 = nullptr; int h0s32 = 0;
    const f16* h1_16;
    if (j == 0) {
        if (l == 0) { h0_32 = P.H0in + (size_t)t * HH; h0s32 = TT * HH; }
        else        h0_16 = P.pipe_h + ((size_t)((d & 1) * LL + l)) * BB * HH;
        h1_16 = P.H1st_h + (size_t)l * BB * HH;
    } else {
        h0_16 = P.h0m_h + (size_t)l * BB * HH;
        h1_16 = P.h1m_h + (size_t)l * BB * HH;
    }
    const f16* wT = P.linT + (size_t)w * 2048 * 1024;
    const float* bias = P.lin_b + (size_t)w * 2048;
    float* z0 = P.z0b + (size_t)l * BB * 512;
    float* z1 = P.z1b + (size_t)l * BB * 512;
    f16* A0 = P.A0b + (size_t)l * BB * 1024;
    f16* A1 = P.A1b + (size_t)l * BB * 1024;

    const int lane = tid & 63, wid = tid >> 6, wm = wid & 1, wn = wid >> 1;
    const int kc = tid & 7, rb = tid >> 3;
    const int r0 = mh * 64 + rb;

    f32x4 acc[2][2] = {};
    f16x8 pa0, pa1, pb0, pb1;

#define LOAD_S1(k0_) do {                                                     \
    int kk = (k0_) + kc * 8;                                                  \
    if (kk < 512) {                                                           \
        if (h0_16) {                                                          \
            pa0 = *(const f16x8*)(h0_16 + (size_t)r0 * HH + kk);              \
            pa1 = *(const f16x8*)(h0_16 + (size_t)(r0 + 32) * HH + kk);       \
        } else {                                                              \
            pa0 = cvt8(h0_32 + (size_t)r0 * h0s32 + kk);                      \
            pa1 = cvt8(h0_32 + (size_t)(r0 + 32) * h0s32 + kk);               \
        }                                                                     \
    } else {                                                                  \
        pa0 = *(const f16x8*)(h1_16 + (size_t)r0 * HH + kk - 512);            \
        pa1 = *(const f16x8*)(h1_16 + (size_t)(r0 + 32) * HH + kk - 512);     \
    }                                                                         \
    pb0 = *(const f16x8*)(wT + (size_t)(n0 + rb) * 1024 + (k0_) + kc * 8);    \
    pb1 = *(const f16x8*)(wT + (size_t)(n0 + rb + 32) * 1024 + (k0_) + kc * 8);\
} while (0)

    LOAD_S1(0);
    for (int k0 = 0; k0 < 1024; k0 += 64) {
        *(f16x8*)(&Al[rb][kc * 8])      = pa0;
        *(f16x8*)(&Al[rb + 32][kc * 8]) = pa1;
        *(f16x8*)(&Bl[rb][kc * 8])      = pb0;
        *(f16x8*)(&Bl[rb + 32][kc * 8]) = pb1;
        __syncthreads();
        if (k0 + 64 < 1024) LOAD_S1(k0 + 64);
#pragma unroll
        for (int ks = 0; ks < 64; ks += 32) {
            const int kl = ks + (lane >> 4) * 8;
            f16x8 af[2], bf[2];
            af[0] = *(const f16x8*)(&Al[wm * 32 + (lane & 15)][kl]);
            af[1] = *(const f16x8*)(&Al[wm * 32 + 16 + (lane & 15)][kl]);
            bf[0] = *(const f16x8*)(&Bl[wn * 32 + (lane & 15)][kl]);
            bf[1] = *(const f16x8*)(&Bl[wn * 32 + 16 + (lane & 15)][kl]);
#pragma unroll
            for (int fm = 0; fm < 2; fm++)
#pragma unroll
                for (int fn = 0; fn < 2; fn++)
                    acc[fm][fn] = __builtin_amdgcn_mfma_f32_16x16x32_f16(
                        af[fm], bf[fn], acc[fm][fn], 0, 0, 0);
        }
        __syncthreads();
    }
#undef LOAD_S1

    const int cls = n0 >> 9;
#pragma unroll
    for (int fm = 0; fm < 2; fm++) {
#pragma unroll
        for (int fn = 0; fn < 2; fn++) {
#pragma unroll
            for (int r = 0; r < 4; r++) {
                int m = mh * 64 + wm * 32 + fm * 16 + (lane >> 4) * 4 + r;
                int n = n0 + wn * 32 + fn * 16 + (lane & 15);
                float x = acc[fm][fn][r] + bias[n];
                float s = 1.0f / (1.0f + __expf(-x));
                int nn = n & 511;
                if (cls == 0) {
                    z0[m * 512 + nn] = s;
                    float h0v = h0_16 ? (float)h0_16[(size_t)m * HH + nn]
                                      : h0_32[(size_t)m * h0s32 + nn];
                    A0[m * 1024 + nn] = (f16)h0v;
                } else if (cls == 1) {
                    z1[m * 512 + nn] = s;
                    A1[m * 1024 + nn] = h1_16[(size_t)m * HH + nn];
                } else if (cls == 2) {
                    float h1v = (float)h1_16[(size_t)m * HH + nn];
                    A0[m * 1024 + 512 + nn] = (f16)(h1v * s);
                } else {
                    float h0v = h0_16 ? (float)h0_16[(size_t)m * HH + nn]
                                      : h0_32[(size_t)m * h0s32 + nn];
                    A1[m * 1024 + 512 + nn] = (f16)(h0v * s);
                }
            }
        }
    }
}

// ---------------------------------------------------------------------------
// Stage 2 (per unit = 64x32 tile of one cell's g0- or g1-GEMM):
// hc = tanh(A @ gw + gb); dst = z*hc + (1-z)*old
// unit u: ci=u>>6, ge=(u>>5)&1, mh=(u>>4)&1, nt=u&15
// ---------------------------------------------------------------------------
__device__ void stage2(const KP& P, int d, int j, int lmin,
                       f16 (*Al)[72], f16 (*Bl)[72])
{
    const int tid = threadIdx.x;
    const int u = blockIdx.x;
    const int nt = u & 15, mh = (u >> 4) & 1, ge = (u >> 5) & 1, ci = u >> 6;
    const int l = lmin + ci, t = d - l, w = l * JJ + j;
    const int n0 = nt * 32;

    const f16* A = (ge ? P.A1b : P.A0b) + (size_t)l * BB * 1024;
    const f16* wTg = (ge ? P.g1T : P.g0T) + (size_t)w * 512 * 1024;
    const float* bs = (ge ? P.g1_b : P.g0_b) + (size_t)w * 512;
    const float* z = (ge ? P.z0b : P.z1b) + (size_t)l * BB * 512;

    const float* oldp; int olds;
    float* dst; int dsts; f16* dsth;
    if (!ge) {  // g0 -> new h1 (gate z1, old = h1)
        if (j == 0) {
            oldp = P.H1st + l * HH; olds = LL * HH;
            dst = P.h1m + (size_t)l * BB * HH; dsts = HH;
            dsth = P.h1m_h + (size_t)l * BB * HH;
        } else {
            oldp = P.h1m + (size_t)l * BB * HH; olds = HH;
            dst = P.H1st + l * HH; dsts = LL * HH;
            dsth = P.H1st_h + (size_t)l * BB * HH;
        }
    } else {    // g1 -> new h0 (gate z0, old = h0)
        if (j == 0) {
            if (l == 0) { oldp = P.H0in + (size_t)t * HH; olds = TT * HH; }
            else { oldp = P.pipe + ((size_t)((d & 1) * LL + l)) * BB * HH; olds = HH; }
            dst = P.h0m + (size_t)l * BB * HH; dsts = HH;
            dsth = P.h0m_h + (size_t)l * BB * HH;
        } else {
            oldp = P.h0m + (size_t)l * BB * HH; olds = HH;
            if (l == LL - 1) {
                dst = P.H0out + (size_t)t * HH; dsts = TT * HH; dsth = nullptr;
            } else {
                size_t off = ((size_t)(((d + 1) & 1) * LL + (l + 1))) * BB * HH;
                dst = P.pipe + off; dsts = HH; dsth = P.pipe_h + off;
            }
        }
    }

    const int lane = tid & 63, wid = tid >> 6, wm = wid & 1, wn = wid >> 1;
    const int kc = tid & 7, rb = tid >> 3;
    const int r0 = mh * 64 + rb;

    f32x4 acc[2] = {};
    f16x8 pa0, pa1, pb0;

#define LOAD_S2(k0_) do {                                                     \
    pa0 = *(const f16x8*)(A + (size_t)r0 * 1024 + (k0_) + kc * 8);            \
    pa1 = *(const f16x8*)(A + (size_t)(r0 + 32) * 1024 + (k0_) + kc * 8);     \
    pb0 = *(const f16x8*)(wTg + (size_t)(n0 + rb) * 1024 + (k0_) + kc * 8);   \
} while (0)

    LOAD_S2(0);
    for (int k0 = 0; k0 < 1024; k0 += 64) {
        *(f16x8*)(&Al[rb][kc * 8])      = pa0;
        *(f16x8*)(&Al[rb + 32][kc * 8]) = pa1;
        *(f16x8*)(&Bl[rb][kc * 8])      = pb0;
        __syncthreads();
        if (k0 + 64 < 1024) LOAD_S2(k0 + 64);
#pragma unroll
        for (int ks = 0; ks < 64; ks += 32) {
            const int kl = ks + (lane >> 4) * 8;
            f16x8 bf  = *(const f16x8*)(&Bl[wn * 16 + (lane & 15)][kl]);
            f16x8 af0 = *(const f16x8*)(&Al[wm * 32 + (lane & 15)][kl]);
            f16x8 af1 = *(const f16x8*)(&Al[wm * 32 + 16 + (lane & 15)][kl]);
            acc[0] = __builtin_amdgcn_mfma_f32_16x16x32_f16(af0, bf, acc[0], 0, 0, 0);
            acc[1] = __builtin_amdgcn_mfma_f32_16x16x32_f16(af1, bf, acc[1], 0, 0, 0);
        }
        __syncthreads();
    }
#undef LOAD_S2

#pragma unroll
    for (int fm = 0; fm < 2; fm++) {
#pragma unroll
        for (int r = 0; r < 4; r++) {
            int m = mh * 64 + wm * 32 + fm * 16 + (lane >> 4) * 4 + r;
            int n = n0 + wn * 16 + (lane & 15);
            float hc = tanhf(acc[fm][r] + bs[n]);
            float zv = z[m * 512 + n];
            float old = oldp[(size_t)m * olds + n];
            float nv = zv * hc + (1.0f - zv) * old;
            dst[(size_t)m * dsts + n] = nv;
            if (dsth) dsth[(size_t)m * HH + n] = (f16)nv;
        }
    }
}

// ---------------------------------------------------------------------------
// Persistent kernel, normal launch. 256 blocks x 256 threads (>=1 block/CU
// capacity everywhere -> all blocks co-resident; hand-rolled barriers).
// Within a diagonal all deps are same-cell -> 64-block sub-barriers (cell ci
// always runs on blocks [64ci,64ci+64)). Only the diagonal boundary needs the
// full 256-block barrier (pipe / H1st handoff across cells).
// ---------------------------------------------------------------------------
__global__ __launch_bounds__(256) void lattice_persistent(KP P)
{
    __shared__ __attribute__((aligned(16))) f16 Al[64][72];
    __shared__ __attribute__((aligned(16))) f16 Bl[64][72];

    const int blk = blockIdx.x;
    const int ci = blk >> 6;
    unsigned* cellbar = P.bars + (size_t)ci * 16;
    unsigned* gridbar = P.bars + (size_t)4 * 16;

    for (int d = 0; d < TT + LL - 1; ++d) {
        int lmin = d - (TT - 1); if (lmin < 0) lmin = 0;
        int lmax = d < LL - 1 ? d : LL - 1;
        int nu = (lmax - lmin + 1) * 64;
        bool act = blk < nu;
        for (int j = 0; j < JJ; ++j) {
            if (act) {
                stage1(P, d, j, lmin, Al, Bl);
                gbar(cellbar, 64);
                stage2(P, d, j, lmin, Al, Bl);
                if (j == 0) gbar(cellbar, 64);
            }
        }
        gbar(gridbar, NBLK);
    }
}

// ---------------------------------------------------------------------------
extern "C" void kernel_launch(void* const* d_in, const int* in_sizes, int n_in,
                              void* d_out, int out_size, void* d_ws, size_t ws_size,
                              hipStream_t stream)
{
    (void)in_sizes; (void)n_in; (void)out_size; (void)ws_size;

    const float* H0in  = (const float*)d_in[0];
    const float* lin_w = (const float*)d_in[1];
    const float* lin_b = (const float*)d_in[2];
    const float* g0_w  = (const float*)d_in[3];
    const float* g0_b  = (const float*)d_in[4];
    const float* g1_w  = (const float*)d_in[5];
    const float* g1_b  = (const float*)d_in[6];

    float* H0out = (float*)d_out;                 // (B,T,H)
    float* H1st  = H0out + (size_t)BB * TT * HH;  // (B,L,H)

    char* p = (char*)d_ws;
    f16* linT   = (f16*)p;   p += (size_t)LL * JJ * 2048 * 1024 * sizeof(f16);
    f16* g0T    = (f16*)p;   p += (size_t)LL * JJ * 512 * 1024 * sizeof(f16);
    f16* g1T    = (f16*)p;   p += (size_t)LL * JJ * 512 * 1024 * sizeof(f16);
    f16* A0b    = (f16*)p;   p += (size_t)LL * BB * 1024 * sizeof(f16);
    f16* A1b    = (f16*)p;   p += (size_t)LL * BB * 1024 * sizeof(f16);
    float* z0b  = (float*)p; p += (size_t)LL * BB * 512 * sizeof(float);
    float* z1b  = (float*)p; p += (size_t)LL * BB * 512 * sizeof(float);
    float* h0m  = (float*)p; p += (size_t)LL * BB * HH * sizeof(float);
    float* h1m  = (float*)p; p += (size_t)LL * BB * HH * sizeof(float);
    f16* h0m_h  = (f16*)p;   p += (size_t)LL * BB * HH * sizeof(f16);
    f16* h1m_h  = (f16*)p;   p += (size_t)LL * BB * HH * sizeof(f16);
    float* pipe = (float*)p; p += (size_t)2 * LL * BB * HH * sizeof(float);
    f16* pipe_h = (f16*)p;   p += (size_t)2 * LL * BB * HH * sizeof(f16);
    f16* H1st_h = (f16*)p;   p += (size_t)LL * BB * HH * sizeof(f16);
    unsigned* bars = (unsigned*)p; p += 5 * 16 * sizeof(unsigned);

    wt_transpose_cvt<<<dim3(32, 64, 8), 256, 0, stream>>>(lin_w, linT, 1024, 2048);
    wt_transpose_cvt<<<dim3(32, 16, 8), 256, 0, stream>>>(g0_w,  g0T,  1024, 512);
    wt_transpose_cvt<<<dim3(32, 16, 8), 256, 0, stream>>>(g1_w,  g1T,  1024, 512);
    hipMemsetAsync(H1st, 0, (size_t)BB * LL * HH * sizeof(float), stream);
    hipMemsetAsync(H1st_h, 0, (size_t)LL * BB * HH * sizeof(f16), stream);
    hipMemsetAsync(bars, 0, 5 * 16 * sizeof(unsigned), stream);

    KP kp;
    kp.H0in = H0in; kp.lin_b = lin_b; kp.g0_b = g0_b; kp.g1_b = g1_b;
    kp.linT = linT; kp.g0T = g0T; kp.g1T = g1T;
    kp.H0out = H0out; kp.H1st = H1st; kp.H1st_h = H1st_h;
    kp.A0b = A0b; kp.A1b = A1b; kp.z0b = z0b; kp.z1b = z1b;
    kp.h0m = h0m; kp.h1m = h1m; kp.h0m_h = h0m_h; kp.h1m_h = h1m_h;
    kp.pipe = pipe; kp.pipe_h = pipe_h; kp.bars = bars;

    lattice_persistent<<<dim3(NBLK), dim3(256), 0, stream>>>(kp);
}